// Round 5
// baseline (4016.027 us; speedup 1.0000x reference)
//
#include <hip/hip_runtime.h>
#include <cstdint>
#include <cstddef>

#define CH    1024
#define LAT   128
#define NBLK  256   // one block per CU; block owns 4 hidden dims (16 gate rows)

// ---------------- ws layout (bytes) ----------------
// [0, 32 KiB)    : hbuf64[2][2048] tagged h broadcast, PADDED: block b -> [b*8, b*8+4)
// [+32 KiB]      : hfin64[1024]    tagged final h (tag==1)
// [+40 KiB]      : cfin64[1024]    tagged final c (tag==1)
// [+48 KiB]      : ctrl[1]         {eos_idx}
// [64 KiB, +16M) : xg[1024][4096]  precomputed input gates (biases INCLUDED here,
//                                  and ONLY here — lstm_k must not re-add them)
#define WS_HBUF  0
#define WS_HFIN  32768
#define WS_CFIN  (32768 + 8192)
#define WS_CTRL  (32768 + 16384)
#define WS_XG    65536

__device__ __forceinline__ float sigmf(float x) { return 1.0f / (1.0f + expf(-x)); }

// ---------------- kernel A: eos index ----------------
__global__ __launch_bounds__(1024) void setup_k(const int* __restrict__ tok,
                                                int* __restrict__ ctrl) {
  __shared__ int red[1024];
  int tid = threadIdx.x;
  red[tid] = (tok[tid] == 1) ? tid : 0x7fffffff;
  __syncthreads();
  for (int s = 512; s > 0; s >>= 1) {
    if (tid < s) red[tid] = min(red[tid], red[tid + s]);
    __syncthreads();
  }
  if (tid == 0) {
    int e = red[0];
    ctrl[0] = (e == 0x7fffffff) ? 0 : e;
  }
}

// ---------------- kernel B: xg = gather(emb) @ W_ih^T + b_ih + b_hh ----------------
// Tiles 128(t) x 128(r), 256 threads, 8x8 microtile, K-chunk 16.
__global__ __launch_bounds__(256) void xgemm_k(const int* __restrict__ tok,
                                               const float* __restrict__ emb,
                                               const float* __restrict__ Wih,
                                               const float* __restrict__ bih,
                                               const float* __restrict__ bhh,
                                               float* __restrict__ xg) {
  __shared__ float As[16 * 132];   // As[k][m], pad 132
  __shared__ float Bs[16 * 132];   // Bs[k][n]
  const int tid = threadIdx.x;
  const int r0 = blockIdx.x * 128;
  const int t0 = blockIdx.y * 128;
  const int tx = tid & 15, ty = tid >> 4;
  const int m0 = ty * 8, n0 = tx * 8;
  const int lrow = tid >> 1;            // 0..127 loader row
  const int kq   = (tid & 1) * 8;       // 0 or 8

  float acc[8][8];
#pragma unroll
  for (int i = 0; i < 8; i++)
#pragma unroll
    for (int j = 0; j < 8; j++) acc[i][j] = 0.0f;

  const int tokv = tok[t0 + lrow];
  const float* arow = emb + (size_t)tokv * CH;
  const float* brow = Wih + (size_t)(r0 + lrow) * CH;

  for (int k0 = 0; k0 < CH; k0 += 16) {
    float4 a0 = *(const float4*)(arow + k0 + kq);
    float4 a1 = *(const float4*)(arow + k0 + kq + 4);
    float4 b0 = *(const float4*)(brow + k0 + kq);
    float4 b1 = *(const float4*)(brow + k0 + kq + 4);
    __syncthreads();
    As[(kq + 0) * 132 + lrow] = a0.x;
    As[(kq + 1) * 132 + lrow] = a0.y;
    As[(kq + 2) * 132 + lrow] = a0.z;
    As[(kq + 3) * 132 + lrow] = a0.w;
    As[(kq + 4) * 132 + lrow] = a1.x;
    As[(kq + 5) * 132 + lrow] = a1.y;
    As[(kq + 6) * 132 + lrow] = a1.z;
    As[(kq + 7) * 132 + lrow] = a1.w;
    Bs[(kq + 0) * 132 + lrow] = b0.x;
    Bs[(kq + 1) * 132 + lrow] = b0.y;
    Bs[(kq + 2) * 132 + lrow] = b0.z;
    Bs[(kq + 3) * 132 + lrow] = b0.w;
    Bs[(kq + 4) * 132 + lrow] = b1.x;
    Bs[(kq + 5) * 132 + lrow] = b1.y;
    Bs[(kq + 6) * 132 + lrow] = b1.z;
    Bs[(kq + 7) * 132 + lrow] = b1.w;
    __syncthreads();
#pragma unroll
    for (int kk = 0; kk < 16; kk++) {
      float4 av0 = *(const float4*)&As[kk * 132 + m0];
      float4 av1 = *(const float4*)&As[kk * 132 + m0 + 4];
      float4 bv0 = *(const float4*)&Bs[kk * 132 + n0];
      float4 bv1 = *(const float4*)&Bs[kk * 132 + n0 + 4];
      float aa[8] = {av0.x, av0.y, av0.z, av0.w, av1.x, av1.y, av1.z, av1.w};
      float bb[8] = {bv0.x, bv0.y, bv0.z, bv0.w, bv1.x, bv1.y, bv1.z, bv1.w};
#pragma unroll
      for (int i = 0; i < 8; i++)
#pragma unroll
        for (int j = 0; j < 8; j++) acc[i][j] += aa[i] * bb[j];
    }
  }

  float4 bi0 = *(const float4*)(bih + r0 + n0);
  float4 bi1 = *(const float4*)(bih + r0 + n0 + 4);
  float4 bh0 = *(const float4*)(bhh + r0 + n0);
  float4 bh1 = *(const float4*)(bhh + r0 + n0 + 4);
  float badd[8] = {bi0.x + bh0.x, bi0.y + bh0.y, bi0.z + bh0.z, bi0.w + bh0.w,
                   bi1.x + bh1.x, bi1.y + bh1.y, bi1.z + bh1.z, bi1.w + bh1.w};
#pragma unroll
  for (int i = 0; i < 8; i++) {
    float4 o0 = {acc[i][0] + badd[0], acc[i][1] + badd[1],
                 acc[i][2] + badd[2], acc[i][3] + badd[3]};
    float4 o1 = {acc[i][4] + badd[4], acc[i][5] + badd[5],
                 acc[i][6] + badd[6], acc[i][7] + badd[7]};
    float* dst = xg + (size_t)(t0 + m0 + i) * 4096 + r0 + n0;
    *(float4*)(dst) = o0;
    *(float4*)(dst + 4) = o1;
  }
}

// ---------------- kernel C: cooperative LSTM recurrence + projections ----------------
// 256 blocks x 256 threads (4 waves). Wave w owns hidden dim d = b*4+w.
// Lane l: gate q=l>>4 (i,f,g,o), k-chunk m=l&15 (64 contiguous k).
// Only W_hh row-slice (64 floats) is register-persistent -> no spills.
// xg is precomputed WITH biases; lane m==0 prefetches next step's value
// after publish (off the critical path). NO bias add here (would double-add).
// Cross-block h exchange: fence-free tagged u64 relaxed agent-scope atomics;
// hbuf padded to one 64B line per block (stride 8, 4 valid) -> no false sharing.
__global__ __launch_bounds__(256, 1) void lstm_k(const float* __restrict__ h0,
                                                 const float* __restrict__ c0,
                                                 const float* __restrict__ eps,
                                                 const float* __restrict__ Whh,
                                                 const float* __restrict__ Wm,
                                                 const float* __restrict__ bm,
                                                 const float* __restrict__ Wl,
                                                 const float* __restrict__ bl,
                                                 const float* __restrict__ xg,
                                                 unsigned long long* __restrict__ hbuf64,
                                                 unsigned long long* __restrict__ hfin64,
                                                 unsigned long long* __restrict__ cfin64,
                                                 const int* __restrict__ ctrl,
                                                 float* __restrict__ out) {
  __shared__ float hs[2][1088];   // swizzled: hs[slot][m*68 + j] = h[m*64+j]
  __shared__ float hcs[2048];
  __shared__ float rs[8];

  const int tid = threadIdx.x;          // 0..255
  const int b   = blockIdx.x;           // 0..255
  const int w   = tid >> 6;             // wave 0..3
  const int l   = tid & 63;
  const int q   = l >> 4;               // gate: 0=i 1=f 2=g 3=o
  const int m   = l & 15;               // k-chunk
  const int d   = b * 4 + w;            // hidden dim owned by this wave
  const int r   = q * 1024 + d;         // gate row

  // ---- load W_hh slice into registers ----
  float wh[64];
  {
    const float* php = Whh + (size_t)r * CH + m * 64;
#pragma unroll
    for (int i = 0; i < 64; i += 4) {
      float4 a = *(const float4*)(php + i);
      wh[i] = a.x; wh[i + 1] = a.y; wh[i + 2] = a.z; wh[i + 3] = a.w;
    }
  }
  const int eos = ctrl[0];

  float creg = c0[d];
  float hreg = h0[d];

  // prefetch xg for t=0 (valid at lanes m==0; includes biases)
  float xvp = 0.0f;
  if (m == 0 && eos > 0) xvp = xg[r];

  for (int t = 0; t < eos; t++) {
    // ---- fill hs[t&1]: thread polls its block-line (4 tagged u64) ----
    float4 hv;
    if (t == 0) {
      hv = *(const float4*)(h0 + tid * 4);
    } else {
      const unsigned want = (unsigned)t;
      const unsigned long long* src = hbuf64 + (size_t)(t & 1) * 2048 + tid * 8;
      unsigned long long v0, v1, v2, v3;
      bool ok;
      do {
        v0 = __hip_atomic_load(src + 0, __ATOMIC_RELAXED, __HIP_MEMORY_SCOPE_AGENT);
        v1 = __hip_atomic_load(src + 1, __ATOMIC_RELAXED, __HIP_MEMORY_SCOPE_AGENT);
        v2 = __hip_atomic_load(src + 2, __ATOMIC_RELAXED, __HIP_MEMORY_SCOPE_AGENT);
        v3 = __hip_atomic_load(src + 3, __ATOMIC_RELAXED, __HIP_MEMORY_SCOPE_AGENT);
        ok = ((unsigned)(v0 >> 32) == want) & ((unsigned)(v1 >> 32) == want) &
             ((unsigned)(v2 >> 32) == want) & ((unsigned)(v3 >> 32) == want);
      } while (!ok);
      hv.x = __uint_as_float((unsigned)v0);
      hv.y = __uint_as_float((unsigned)v1);
      hv.z = __uint_as_float((unsigned)v2);
      hv.w = __uint_as_float((unsigned)v3);
    }
    *(float4*)&hs[t & 1][(tid >> 4) * 68 + (tid & 15) * 4] = hv;
    __syncthreads();

    // ---- matvec: acc = dot(wh, h_slice) ----
    const float* hp = &hs[t & 1][m * 68];
    float acc = 0.0f;
#pragma unroll
    for (int i = 0; i < 64; i += 4) {
      float4 h4 = *(const float4*)(hp + i);
      acc += wh[i] * h4.x + wh[i + 1] * h4.y + wh[i + 2] * h4.z + wh[i + 3] * h4.w;
    }
    // reduce within 16-lane gate groups
    acc += __shfl_xor(acc, 1);
    acc += __shfl_xor(acc, 2);
    acc += __shfl_xor(acc, 4);
    acc += __shfl_xor(acc, 8);
    float accb = acc + xvp;                   // xvp (with biases) valid at lanes m==0
    float iv = __shfl(accb, 0);
    float fv = __shfl(accb, 16);
    float gv = __shfl(accb, 32);
    float ov = __shfl(accb, 48);
    float cn = sigmf(fv) * creg + sigmf(iv) * tanhf(gv);
    float hn = sigmf(ov) * tanhf(cn);
    creg = cn;
    hreg = hn;
    if (l == 0) {
      unsigned long long pv = ((unsigned long long)(unsigned)(t + 1) << 32) |
                              (unsigned long long)__float_as_uint(hn);
      __hip_atomic_store(&hbuf64[(size_t)((t + 1) & 1) * 2048 + b * 8 + w], pv,
                         __ATOMIC_RELAXED, __HIP_MEMORY_SCOPE_AGENT);
    }
    // ---- off-critical-path: prefetch next step's xg value ----
    if (m == 0 && t + 1 < eos) xvp = xg[(size_t)(t + 1) * 4096 + r];
  }

  // ---- publish final h, c (tag == 1) ----
  if (l == 0) {
    unsigned long long ph = (1ull << 32) | (unsigned long long)__float_as_uint(hreg);
    unsigned long long pc = (1ull << 32) | (unsigned long long)__float_as_uint(creg);
    __hip_atomic_store(&hfin64[d], ph, __ATOMIC_RELAXED, __HIP_MEMORY_SCOPE_AGENT);
    __hip_atomic_store(&cfin64[d], pc, __ATOMIC_RELAXED, __HIP_MEMORY_SCOPE_AGENT);
  }
  if (b >= LAT) return;   // blocks 128..255 done

  // ---- gather hc = concat(h, c) ----
  {
    const unsigned long long* hp = hfin64 + tid * 4;
    const unsigned long long* cp = cfin64 + tid * 4;
    unsigned long long v0, v1, v2, v3;
    bool ok;
    do {
      v0 = __hip_atomic_load(hp + 0, __ATOMIC_RELAXED, __HIP_MEMORY_SCOPE_AGENT);
      v1 = __hip_atomic_load(hp + 1, __ATOMIC_RELAXED, __HIP_MEMORY_SCOPE_AGENT);
      v2 = __hip_atomic_load(hp + 2, __ATOMIC_RELAXED, __HIP_MEMORY_SCOPE_AGENT);
      v3 = __hip_atomic_load(hp + 3, __ATOMIC_RELAXED, __HIP_MEMORY_SCOPE_AGENT);
      ok = ((unsigned)(v0 >> 32) == 1u) & ((unsigned)(v1 >> 32) == 1u) &
           ((unsigned)(v2 >> 32) == 1u) & ((unsigned)(v3 >> 32) == 1u);
    } while (!ok);
    hcs[tid * 4 + 0] = __uint_as_float((unsigned)v0);
    hcs[tid * 4 + 1] = __uint_as_float((unsigned)v1);
    hcs[tid * 4 + 2] = __uint_as_float((unsigned)v2);
    hcs[tid * 4 + 3] = __uint_as_float((unsigned)v3);
    do {
      v0 = __hip_atomic_load(cp + 0, __ATOMIC_RELAXED, __HIP_MEMORY_SCOPE_AGENT);
      v1 = __hip_atomic_load(cp + 1, __ATOMIC_RELAXED, __HIP_MEMORY_SCOPE_AGENT);
      v2 = __hip_atomic_load(cp + 2, __ATOMIC_RELAXED, __HIP_MEMORY_SCOPE_AGENT);
      v3 = __hip_atomic_load(cp + 3, __ATOMIC_RELAXED, __HIP_MEMORY_SCOPE_AGENT);
      ok = ((unsigned)(v0 >> 32) == 1u) & ((unsigned)(v1 >> 32) == 1u) &
           ((unsigned)(v2 >> 32) == 1u) & ((unsigned)(v3 >> 32) == 1u);
    } while (!ok);
    hcs[1024 + tid * 4 + 0] = __uint_as_float((unsigned)v0);
    hcs[1024 + tid * 4 + 1] = __uint_as_float((unsigned)v1);
    hcs[1024 + tid * 4 + 2] = __uint_as_float((unsigned)v2);
    hcs[1024 + tid * 4 + 3] = __uint_as_float((unsigned)v3);
  }
  __syncthreads();

  // ---- projections: mean[b], logv[b] (2048-dot each over 256 threads) ----
  float pm = 0.0f, pl = 0.0f;
  {
    const float* wmp = Wm + (size_t)b * 2048 + tid * 8;
    const float* wlp = Wl + (size_t)b * 2048 + tid * 8;
    const float* hcp = &hcs[tid * 8];
#pragma unroll
    for (int j = 0; j < 8; j += 4) {
      float4 wm4 = *(const float4*)(wmp + j);
      float4 wl4 = *(const float4*)(wlp + j);
      float4 hc4 = *(const float4*)(hcp + j);
      pm += wm4.x * hc4.x + wm4.y * hc4.y + wm4.z * hc4.z + wm4.w * hc4.w;
      pl += wl4.x * hc4.x + wl4.y * hc4.y + wl4.z * hc4.z + wl4.w * hc4.w;
    }
  }
#pragma unroll
  for (int o = 32; o > 0; o >>= 1) {
    pm += __shfl_down(pm, o);
    pl += __shfl_down(pl, o);
  }
  if (l == 0) { rs[w] = pm; rs[4 + w] = pl; }
  __syncthreads();
  if (tid == 0) {
    float mval = rs[0] + rs[1] + rs[2] + rs[3] + bm[b];
    float lval = rs[4] + rs[5] + rs[6] + rs[7] + bl[b];
    float z = eps[b] * expf(0.5f * lval) + mval;
    out[b] = z;
    out[LAT + b] = mval;
    out[2 * LAT + b] = lval;
  }
}

extern "C" void kernel_launch(void* const* d_in, const int* in_sizes, int n_in,
                              void* d_out, int out_size, void* d_ws, size_t ws_size,
                              hipStream_t stream) {
  const int*   tok = (const int*)d_in[0];
  const float* h0  = (const float*)d_in[1];
  const float* c0  = (const float*)d_in[2];
  const float* eps = (const float*)d_in[3];
  const float* emb = (const float*)d_in[4];
  const float* Wih = (const float*)d_in[5];
  const float* Whh = (const float*)d_in[6];
  const float* bih = (const float*)d_in[7];
  const float* bhh = (const float*)d_in[8];
  const float* Wm  = (const float*)d_in[9];
  const float* bm  = (const float*)d_in[10];
  const float* Wl  = (const float*)d_in[11];
  const float* bl  = (const float*)d_in[12];
  float* out = (float*)d_out;

  char* ws = (char*)d_ws;
  unsigned long long* hbuf64 = (unsigned long long*)(ws + WS_HBUF);
  unsigned long long* hfin64 = (unsigned long long*)(ws + WS_HFIN);
  unsigned long long* cfin64 = (unsigned long long*)(ws + WS_CFIN);
  int*   ctrl = (int*)(ws + WS_CTRL);
  float* xg   = (float*)(ws + WS_XG);

  setup_k<<<1, 1024, 0, stream>>>(tok, ctrl);
  xgemm_k<<<dim3(4096 / 128, 1024 / 128), 256, 0, stream>>>(tok, emb, Wih, bih, bhh, xg);

  void* args[] = {(void*)&h0, (void*)&c0, (void*)&eps, (void*)&Whh,
                  (void*)&Wm, (void*)&bm, (void*)&Wl, (void*)&bl,
                  (void*)&xg, (void*)&hbuf64, (void*)&hfin64, (void*)&cfin64,
                  (void*)&ctrl, (void*)&out};
  hipLaunchCooperativeKernel((void*)lstm_k, dim3(NBLK), dim3(256), args, 0, stream);
}

// Round 6
// 3022.713 us; speedup vs baseline: 1.3286x; 1.3286x over previous
//
#include <hip/hip_runtime.h>
#include <cstdint>
#include <cstddef>

#define CH    1024
#define LAT   128
#define NBLK  256   // one block per CU; block owns 4 hidden dims (16 gate rows)

// ---------------- ws layout (bytes) ----------------
// [0, 16 KiB)    : hbuf64[2][1024] tagged h broadcast, UNPADDED (block b -> [4b,4b+4))
// [+16 KiB]      : hfin64[1024]    tagged final h (tag==1)
// [+24 KiB]      : cfin64[1024]    tagged final c (tag==1)
// [+32 KiB]      : ctrl[1]         {eos_idx}
// [64 KiB, +16M) : xg[1024][4096]  precomputed input gates (biases INCLUDED here,
//                                  and ONLY here — lstm_k must not re-add them)
#define WS_HBUF  0
#define WS_HFIN  16384
#define WS_CFIN  (16384 + 8192)
#define WS_CTRL  32768
#define WS_XG    65536

__device__ __forceinline__ float sigmf(float x) { return 1.0f / (1.0f + expf(-x)); }

// ---------------- kernel A: eos index ----------------
__global__ __launch_bounds__(1024) void setup_k(const int* __restrict__ tok,
                                                int* __restrict__ ctrl) {
  __shared__ int red[1024];
  int tid = threadIdx.x;
  red[tid] = (tok[tid] == 1) ? tid : 0x7fffffff;
  __syncthreads();
  for (int s = 512; s > 0; s >>= 1) {
    if (tid < s) red[tid] = min(red[tid], red[tid + s]);
    __syncthreads();
  }
  if (tid == 0) {
    int e = red[0];
    ctrl[0] = (e == 0x7fffffff) ? 0 : e;
  }
}

// ---------------- kernel B: xg = gather(emb) @ W_ih^T + b_ih + b_hh ----------------
// Tiles 128(t) x 128(r), 256 threads, 8x8 microtile, K-chunk 16.
__global__ __launch_bounds__(256) void xgemm_k(const int* __restrict__ tok,
                                               const float* __restrict__ emb,
                                               const float* __restrict__ Wih,
                                               const float* __restrict__ bih,
                                               const float* __restrict__ bhh,
                                               float* __restrict__ xg) {
  __shared__ float As[16 * 132];   // As[k][m], pad 132
  __shared__ float Bs[16 * 132];   // Bs[k][n]
  const int tid = threadIdx.x;
  const int r0 = blockIdx.x * 128;
  const int t0 = blockIdx.y * 128;
  const int tx = tid & 15, ty = tid >> 4;
  const int m0 = ty * 8, n0 = tx * 8;
  const int lrow = tid >> 1;            // 0..127 loader row
  const int kq   = (tid & 1) * 8;       // 0 or 8

  float acc[8][8];
#pragma unroll
  for (int i = 0; i < 8; i++)
#pragma unroll
    for (int j = 0; j < 8; j++) acc[i][j] = 0.0f;

  const int tokv = tok[t0 + lrow];
  const float* arow = emb + (size_t)tokv * CH;
  const float* brow = Wih + (size_t)(r0 + lrow) * CH;

  for (int k0 = 0; k0 < CH; k0 += 16) {
    float4 a0 = *(const float4*)(arow + k0 + kq);
    float4 a1 = *(const float4*)(arow + k0 + kq + 4);
    float4 b0 = *(const float4*)(brow + k0 + kq);
    float4 b1 = *(const float4*)(brow + k0 + kq + 4);
    __syncthreads();
    As[(kq + 0) * 132 + lrow] = a0.x;
    As[(kq + 1) * 132 + lrow] = a0.y;
    As[(kq + 2) * 132 + lrow] = a0.z;
    As[(kq + 3) * 132 + lrow] = a0.w;
    As[(kq + 4) * 132 + lrow] = a1.x;
    As[(kq + 5) * 132 + lrow] = a1.y;
    As[(kq + 6) * 132 + lrow] = a1.z;
    As[(kq + 7) * 132 + lrow] = a1.w;
    Bs[(kq + 0) * 132 + lrow] = b0.x;
    Bs[(kq + 1) * 132 + lrow] = b0.y;
    Bs[(kq + 2) * 132 + lrow] = b0.z;
    Bs[(kq + 3) * 132 + lrow] = b0.w;
    Bs[(kq + 4) * 132 + lrow] = b1.x;
    Bs[(kq + 5) * 132 + lrow] = b1.y;
    Bs[(kq + 6) * 132 + lrow] = b1.z;
    Bs[(kq + 7) * 132 + lrow] = b1.w;
    __syncthreads();
#pragma unroll
    for (int kk = 0; kk < 16; kk++) {
      float4 av0 = *(const float4*)&As[kk * 132 + m0];
      float4 av1 = *(const float4*)&As[kk * 132 + m0 + 4];
      float4 bv0 = *(const float4*)&Bs[kk * 132 + n0];
      float4 bv1 = *(const float4*)&Bs[kk * 132 + n0 + 4];
      float aa[8] = {av0.x, av0.y, av0.z, av0.w, av1.x, av1.y, av1.z, av1.w};
      float bb[8] = {bv0.x, bv0.y, bv0.z, bv0.w, bv1.x, bv1.y, bv1.z, bv1.w};
#pragma unroll
      for (int i = 0; i < 8; i++)
#pragma unroll
        for (int j = 0; j < 8; j++) acc[i][j] += aa[i] * bb[j];
    }
  }

  float4 bi0 = *(const float4*)(bih + r0 + n0);
  float4 bi1 = *(const float4*)(bih + r0 + n0 + 4);
  float4 bh0 = *(const float4*)(bhh + r0 + n0);
  float4 bh1 = *(const float4*)(bhh + r0 + n0 + 4);
  float badd[8] = {bi0.x + bh0.x, bi0.y + bh0.y, bi0.z + bh0.z, bi0.w + bh0.w,
                   bi1.x + bh1.x, bi1.y + bh1.y, bi1.z + bh1.z, bi1.w + bh1.w};
#pragma unroll
  for (int i = 0; i < 8; i++) {
    float4 o0 = {acc[i][0] + badd[0], acc[i][1] + badd[1],
                 acc[i][2] + badd[2], acc[i][3] + badd[3]};
    float4 o1 = {acc[i][4] + badd[4], acc[i][5] + badd[5],
                 acc[i][6] + badd[6], acc[i][7] + badd[7]};
    float* dst = xg + (size_t)(t0 + m0 + i) * 4096 + r0 + n0;
    *(float4*)(dst) = o0;
    *(float4*)(dst + 4) = o1;
  }
}

// ---------------- kernel C: cooperative LSTM recurrence + projections ----------------
// 256 blocks x 256 threads (4 waves). Wave w owns hidden dim d = b*4+w.
// Lane l: gate q=l>>4 (i,f,g,o), k-chunk m=l&15 (64 contiguous k).
// Only W_hh row-slice (64 floats) is register-persistent -> no spills.
// Publish: waves drop h into LDS, sync, then lanes 0-3 of wave 0 store 4
// CONSECUTIVE tagged u64 -> ONE coalesced 32B transaction (round-5's 4
// per-wave stores cost 4x write-through transactions + skew).
// Poll: thread tid reads 4 consecutive u64 at tid*4 -> wave spins over 2KB
// contiguous (8 lines), not 64 scattered lines like the padded layout.
__global__ __launch_bounds__(256, 1) void lstm_k(const float* __restrict__ h0,
                                                 const float* __restrict__ c0,
                                                 const float* __restrict__ eps,
                                                 const float* __restrict__ Whh,
                                                 const float* __restrict__ Wm,
                                                 const float* __restrict__ bm,
                                                 const float* __restrict__ Wl,
                                                 const float* __restrict__ bl,
                                                 const float* __restrict__ xg,
                                                 unsigned long long* __restrict__ hbuf64,
                                                 unsigned long long* __restrict__ hfin64,
                                                 unsigned long long* __restrict__ cfin64,
                                                 const int* __restrict__ ctrl,
                                                 float* __restrict__ out) {
  __shared__ float hs[2][1088];   // swizzled: hs[slot][m*68 + j] = h[m*64+j]
  __shared__ float hcs[2048];
  __shared__ float gh[4];         // per-wave h for coalesced publish
  __shared__ float ghf[4], gcf[4];
  __shared__ float rs[8];

  const int tid = threadIdx.x;          // 0..255
  const int b   = blockIdx.x;           // 0..255
  const int w   = tid >> 6;             // wave 0..3
  const int l   = tid & 63;
  const int q   = l >> 4;               // gate: 0=i 1=f 2=g 3=o
  const int m   = l & 15;               // k-chunk
  const int d   = b * 4 + w;            // hidden dim owned by this wave
  const int r   = q * 1024 + d;         // gate row

  // ---- load W_hh slice into registers ----
  float wh[64];
  {
    const float* php = Whh + (size_t)r * CH + m * 64;
#pragma unroll
    for (int i = 0; i < 64; i += 4) {
      float4 a = *(const float4*)(php + i);
      wh[i] = a.x; wh[i + 1] = a.y; wh[i + 2] = a.z; wh[i + 3] = a.w;
    }
  }
  const int eos = ctrl[0];

  float creg = c0[d];
  float hreg = h0[d];

  // prefetch xg for t=0 (valid at lanes m==0; includes biases)
  float xvp = 0.0f;
  if (m == 0 && eos > 0) xvp = xg[r];

  for (int t = 0; t < eos; t++) {
    // ---- fill hs[t&1]: thread polls 4 consecutive tagged u64 ----
    float4 hv;
    if (t == 0) {
      hv = *(const float4*)(h0 + tid * 4);
    } else {
      const unsigned want = (unsigned)t;
      const unsigned long long* src = hbuf64 + (size_t)(t & 1) * 1024 + tid * 4;
      unsigned long long v0, v1, v2, v3;
      bool ok;
      do {
        v0 = __hip_atomic_load(src + 0, __ATOMIC_RELAXED, __HIP_MEMORY_SCOPE_AGENT);
        v1 = __hip_atomic_load(src + 1, __ATOMIC_RELAXED, __HIP_MEMORY_SCOPE_AGENT);
        v2 = __hip_atomic_load(src + 2, __ATOMIC_RELAXED, __HIP_MEMORY_SCOPE_AGENT);
        v3 = __hip_atomic_load(src + 3, __ATOMIC_RELAXED, __HIP_MEMORY_SCOPE_AGENT);
        ok = ((unsigned)(v0 >> 32) == want) & ((unsigned)(v1 >> 32) == want) &
             ((unsigned)(v2 >> 32) == want) & ((unsigned)(v3 >> 32) == want);
      } while (!ok);
      hv.x = __uint_as_float((unsigned)v0);
      hv.y = __uint_as_float((unsigned)v1);
      hv.z = __uint_as_float((unsigned)v2);
      hv.w = __uint_as_float((unsigned)v3);
    }
    *(float4*)&hs[t & 1][(tid >> 4) * 68 + (tid & 15) * 4] = hv;
    __syncthreads();

    // ---- matvec: acc = dot(wh, h_slice) ----
    const float* hp = &hs[t & 1][m * 68];
    float acc = 0.0f;
#pragma unroll
    for (int i = 0; i < 64; i += 4) {
      float4 h4 = *(const float4*)(hp + i);
      acc += wh[i] * h4.x + wh[i + 1] * h4.y + wh[i + 2] * h4.z + wh[i + 3] * h4.w;
    }
    // reduce within 16-lane gate groups
    acc += __shfl_xor(acc, 1);
    acc += __shfl_xor(acc, 2);
    acc += __shfl_xor(acc, 4);
    acc += __shfl_xor(acc, 8);
    float accb = acc + xvp;                   // xvp (with biases) valid at lanes m==0
    float iv = __shfl(accb, 0);
    float fv = __shfl(accb, 16);
    float gv = __shfl(accb, 32);
    float ov = __shfl(accb, 48);
    float cn = sigmf(fv) * creg + sigmf(iv) * tanhf(gv);
    float hn = sigmf(ov) * tanhf(cn);
    creg = cn;
    hreg = hn;
    if (l == 0) gh[w] = hn;
    __syncthreads();
    if (tid < 4) {
      unsigned long long pv = ((unsigned long long)(unsigned)(t + 1) << 32) |
                              (unsigned long long)__float_as_uint(gh[tid]);
      __hip_atomic_store(&hbuf64[(size_t)((t + 1) & 1) * 1024 + b * 4 + tid], pv,
                         __ATOMIC_RELAXED, __HIP_MEMORY_SCOPE_AGENT);
    }
    // ---- off-critical-path: prefetch next step's xg value ----
    if (m == 0 && t + 1 < eos) xvp = xg[(size_t)(t + 1) * 4096 + r];
  }

  // ---- publish final h, c (tag == 1), coalesced from wave 0 ----
  if (l == 0) { ghf[w] = hreg; gcf[w] = creg; }
  __syncthreads();
  if (tid < 4) {
    unsigned long long ph = (1ull << 32) | (unsigned long long)__float_as_uint(ghf[tid]);
    unsigned long long pc = (1ull << 32) | (unsigned long long)__float_as_uint(gcf[tid]);
    __hip_atomic_store(&hfin64[b * 4 + tid], ph, __ATOMIC_RELAXED, __HIP_MEMORY_SCOPE_AGENT);
    __hip_atomic_store(&cfin64[b * 4 + tid], pc, __ATOMIC_RELAXED, __HIP_MEMORY_SCOPE_AGENT);
  }
  if (b >= LAT) return;   // blocks 128..255 done

  // ---- gather hc = concat(h, c) ----
  {
    const unsigned long long* hp = hfin64 + tid * 4;
    const unsigned long long* cp = cfin64 + tid * 4;
    unsigned long long v0, v1, v2, v3;
    bool ok;
    do {
      v0 = __hip_atomic_load(hp + 0, __ATOMIC_RELAXED, __HIP_MEMORY_SCOPE_AGENT);
      v1 = __hip_atomic_load(hp + 1, __ATOMIC_RELAXED, __HIP_MEMORY_SCOPE_AGENT);
      v2 = __hip_atomic_load(hp + 2, __ATOMIC_RELAXED, __HIP_MEMORY_SCOPE_AGENT);
      v3 = __hip_atomic_load(hp + 3, __ATOMIC_RELAXED, __HIP_MEMORY_SCOPE_AGENT);
      ok = ((unsigned)(v0 >> 32) == 1u) & ((unsigned)(v1 >> 32) == 1u) &
           ((unsigned)(v2 >> 32) == 1u) & ((unsigned)(v3 >> 32) == 1u);
    } while (!ok);
    hcs[tid * 4 + 0] = __uint_as_float((unsigned)v0);
    hcs[tid * 4 + 1] = __uint_as_float((unsigned)v1);
    hcs[tid * 4 + 2] = __uint_as_float((unsigned)v2);
    hcs[tid * 4 + 3] = __uint_as_float((unsigned)v3);
    do {
      v0 = __hip_atomic_load(cp + 0, __ATOMIC_RELAXED, __HIP_MEMORY_SCOPE_AGENT);
      v1 = __hip_atomic_load(cp + 1, __ATOMIC_RELAXED, __HIP_MEMORY_SCOPE_AGENT);
      v2 = __hip_atomic_load(cp + 2, __ATOMIC_RELAXED, __HIP_MEMORY_SCOPE_AGENT);
      v3 = __hip_atomic_load(cp + 3, __ATOMIC_RELAXED, __HIP_MEMORY_SCOPE_AGENT);
      ok = ((unsigned)(v0 >> 32) == 1u) & ((unsigned)(v1 >> 32) == 1u) &
           ((unsigned)(v2 >> 32) == 1u) & ((unsigned)(v3 >> 32) == 1u);
    } while (!ok);
    hcs[1024 + tid * 4 + 0] = __uint_as_float((unsigned)v0);
    hcs[1024 + tid * 4 + 1] = __uint_as_float((unsigned)v1);
    hcs[1024 + tid * 4 + 2] = __uint_as_float((unsigned)v2);
    hcs[1024 + tid * 4 + 3] = __uint_as_float((unsigned)v3);
  }
  __syncthreads();

  // ---- projections: mean[b], logv[b] (2048-dot each over 256 threads) ----
  float pm = 0.0f, pl = 0.0f;
  {
    const float* wmp = Wm + (size_t)b * 2048 + tid * 8;
    const float* wlp = Wl + (size_t)b * 2048 + tid * 8;
    const float* hcp = &hcs[tid * 8];
#pragma unroll
    for (int j = 0; j < 8; j += 4) {
      float4 wm4 = *(const float4*)(wmp + j);
      float4 wl4 = *(const float4*)(wlp + j);
      float4 hc4 = *(const float4*)(hcp + j);
      pm += wm4.x * hc4.x + wm4.y * hc4.y + wm4.z * hc4.z + wm4.w * hc4.w;
      pl += wl4.x * hc4.x + wl4.y * hc4.y + wl4.z * hc4.z + wl4.w * hc4.w;
    }
  }
#pragma unroll
  for (int o = 32; o > 0; o >>= 1) {
    pm += __shfl_down(pm, o);
    pl += __shfl_down(pl, o);
  }
  if (l == 0) { rs[w] = pm; rs[4 + w] = pl; }
  __syncthreads();
  if (tid == 0) {
    float mval = rs[0] + rs[1] + rs[2] + rs[3] + bm[b];
    float lval = rs[4] + rs[5] + rs[6] + rs[7] + bl[b];
    float z = eps[b] * expf(0.5f * lval) + mval;
    out[b] = z;
    out[LAT + b] = mval;
    out[2 * LAT + b] = lval;
  }
}

extern "C" void kernel_launch(void* const* d_in, const int* in_sizes, int n_in,
                              void* d_out, int out_size, void* d_ws, size_t ws_size,
                              hipStream_t stream) {
  const int*   tok = (const int*)d_in[0];
  const float* h0  = (const float*)d_in[1];
  const float* c0  = (const float*)d_in[2];
  const float* eps = (const float*)d_in[3];
  const float* emb = (const float*)d_in[4];
  const float* Wih = (const float*)d_in[5];
  const float* Whh = (const float*)d_in[6];
  const float* bih = (const float*)d_in[7];
  const float* bhh = (const float*)d_in[8];
  const float* Wm  = (const float*)d_in[9];
  const float* bm  = (const float*)d_in[10];
  const float* Wl  = (const float*)d_in[11];
  const float* bl  = (const float*)d_in[12];
  float* out = (float*)d_out;

  char* ws = (char*)d_ws;
  unsigned long long* hbuf64 = (unsigned long long*)(ws + WS_HBUF);
  unsigned long long* hfin64 = (unsigned long long*)(ws + WS_HFIN);
  unsigned long long* cfin64 = (unsigned long long*)(ws + WS_CFIN);
  int*   ctrl = (int*)(ws + WS_CTRL);
  float* xg   = (float*)(ws + WS_XG);

  setup_k<<<1, 1024, 0, stream>>>(tok, ctrl);
  xgemm_k<<<dim3(4096 / 128, 1024 / 128), 256, 0, stream>>>(tok, emb, Wih, bih, bhh, xg);

  void* args[] = {(void*)&h0, (void*)&c0, (void*)&eps, (void*)&Whh,
                  (void*)&Wm, (void*)&bm, (void*)&Wl, (void*)&bl,
                  (void*)&xg, (void*)&hbuf64, (void*)&hfin64, (void*)&cfin64,
                  (void*)&ctrl, (void*)&out};
  hipLaunchCooperativeKernel((void*)lstm_k, dim3(NBLK), dim3(256), args, 0, stream);
}